// Round 2
// baseline (98.788 us; speedup 1.0000x reference)
//
#include <hip/hip_runtime.h>

#define ALPHA 0.5f
#define BETA 0.5f
#define SMOOTH 1e-6f

constexpr int kB = 32, kC = 4, kH = 512, kW = 512;
constexpr int kHW  = kH * kW;        // 262144
constexpr int kHW4 = kHW / 4;        // 65536 = 2^16
constexpr int kNVEC = kB * kHW4;     // 2097152 float4-groups of pixels
constexpr long long kNPIX = (long long)kB * kHW;  // 8388608

constexpr int kThreads = 256;
constexpr int kBlocks  = 2048;
constexpr int kStride  = kBlocks * kThreads;   // 524288
constexpr int kIters   = kNVEC / kStride;      // 4 (exact)

// ws layout (floats): 13 accumulator slots, each on its own 64B line
// (float index i*16), then the arrival counter at float index 13*16.
constexpr int kSlotStride = 16;
constexpr int kWsFloats = 14 * kSlotStride;

__global__ __launch_bounds__(kThreads) void loss_fused(const float* __restrict__ logits,
                                                       const int* __restrict__ tgt,
                                                       float* __restrict__ ws,
                                                       float* __restrict__ out) {
    const int tid = blockIdx.x * kThreads + threadIdx.x;

    const float4* lg4 = reinterpret_cast<const float4*>(logits);
    const int4*   tg4 = reinterpret_cast<const int4*>(tgt);

    // ---- Load phase: all 20 loads as straight-line code (static indices) ----
    float4 A0[kIters], A1[kIters], A2[kIters], A3[kIters];
    int4   T[kIters];
    #pragma unroll
    for (int k = 0; k < kIters; ++k) {
        int v   = tid + k * kStride;
        int b   = v >> 16;               // v / kHW4
        int hw4 = v & (kHW4 - 1);
        int base = b * (kC * kHW4) + hw4;
        A0[k] = lg4[base];
        A1[k] = lg4[base + kHW4];
        A2[k] = lg4[base + 2 * kHW4];
        A3[k] = lg4[base + 3 * kHW4];
        T[k]  = tg4[b * kHW4 + hw4];
    }

    // ---- Compute phase ----
    float ce = 0.f;
    float ps0 = 0.f, ps1 = 0.f, ps2 = 0.f, ps3 = 0.f;
    float it0 = 0.f, it1 = 0.f, it2 = 0.f, it3 = 0.f;
    unsigned cnt = 0;  // 4 packed byte counters (max 16 per class per thread)

    auto px = [&](float x0, float x1, float x2, float x3, int t) {
        float m  = fmaxf(fmaxf(x0, x1), fmaxf(x2, x3));
        float e0 = __expf(x0 - m);
        float e1 = __expf(x1 - m);
        float e2 = __expf(x2 - m);
        float e3 = __expf(x3 - m);
        float se = e0 + e1 + e2 + e3;
        float inv = __builtin_amdgcn_rcpf(se);
        float xt = (t == 0) ? x0 : (t == 1) ? x1 : (t == 2) ? x2 : x3;
        ce += __logf(se) + (m - xt);
        float p0 = e0 * inv, p1 = e1 * inv, p2 = e2 * inv, p3 = e3 * inv;
        ps0 += p0; ps1 += p1; ps2 += p2; ps3 += p3;
        it0 += (t == 0) ? p0 : 0.f;
        it1 += (t == 1) ? p1 : 0.f;
        it2 += (t == 2) ? p2 : 0.f;
        it3 += (t == 3) ? p3 : 0.f;
        cnt += 1u << (t * 8);
    };

    #pragma unroll
    for (int k = 0; k < kIters; ++k) {
        px(A0[k].x, A1[k].x, A2[k].x, A3[k].x, T[k].x);
        px(A0[k].y, A1[k].y, A2[k].y, A3[k].y, T[k].y);
        px(A0[k].z, A1[k].z, A2[k].z, A3[k].z, T[k].z);
        px(A0[k].w, A1[k].w, A2[k].w, A3[k].w, T[k].w);
    }

    float ct0 = (float)(cnt & 0xff);
    float ct1 = (float)((cnt >> 8) & 0xff);
    float ct2 = (float)((cnt >> 16) & 0xff);
    float ct3 = (float)((cnt >> 24) & 0xff);

    // ---- Block reduction: shuffle tree per wave, LDS across 4 waves ----
    float vals[13] = {ce, ps0, ps1, ps2, ps3, it0, it1, it2, it3, ct0, ct1, ct2, ct3};
    #pragma unroll
    for (int i = 0; i < 13; ++i) {
        float v = vals[i];
        #pragma unroll
        for (int off = 32; off > 0; off >>= 1) v += __shfl_down(v, off);
        vals[i] = v;
    }
    __shared__ float smem[4][13];
    int lane = threadIdx.x & 63;
    int wave = threadIdx.x >> 6;
    if (lane == 0) {
        #pragma unroll
        for (int i = 0; i < 13; ++i) smem[wave][i] = vals[i];
    }
    __syncthreads();
    if (threadIdx.x < 13) {
        float s = smem[0][threadIdx.x] + smem[1][threadIdx.x] +
                  smem[2][threadIdx.x] + smem[3][threadIdx.x];
        atomicAdd(&ws[threadIdx.x * kSlotStride], s);  // one 64B line per slot
    }
    __syncthreads();

    // ---- Last-block finalize ----
    __shared__ int s_last;
    if (threadIdx.x == 0) {
        __threadfence();
        unsigned old = atomicAdd(reinterpret_cast<unsigned*>(ws + 13 * kSlotStride), 1u);
        s_last = (old == (unsigned)(kBlocks - 1));
    }
    __syncthreads();
    if (s_last && threadIdx.x == 0) {
        __threadfence();
        float a[13];
        #pragma unroll
        for (int i = 0; i < 13; ++i) a[i] = atomicAdd(&ws[i * kSlotStride], 0.0f);
        float ce_m = a[0] / (float)kNPIX;
        float dsum = 0.f;
        #pragma unroll
        for (int c = 0; c < 4; ++c) {
            float I = a[5 + c];
            float U = a[1 + c] + a[9 + c];
            dsum += 1.f - (2.f * I + SMOOTH) / (U + SMOOTH);
        }
        float dice = dsum * 0.25f;
        out[0] = ALPHA * ce_m + BETA * dice;
        out[1] = 1.f - dice;
    }
}

extern "C" void kernel_launch(void* const* d_in, const int* in_sizes, int n_in,
                              void* d_out, int out_size, void* d_ws, size_t ws_size,
                              hipStream_t stream) {
    const float* logits = (const float*)d_in[0];
    const int*   tgt    = (const int*)d_in[1];
    float* out = (float*)d_out;
    float* ws  = (float*)d_ws;

    hipMemsetAsync(ws, 0, kWsFloats * sizeof(float), stream);
    loss_fused<<<kBlocks, kThreads, 0, stream>>>(logits, tgt, ws, out);
}

// Round 3
// 43.618 us; speedup vs baseline: 2.2648x; 2.2648x over previous
//
#include <hip/hip_runtime.h>

#define ALPHA 0.5f
#define BETA 0.5f
#define SMOOTH 1e-6f

constexpr int kB = 32, kC = 4, kH = 512, kW = 512;
constexpr int kHW  = kH * kW;        // 262144
constexpr int kHW4 = kHW / 4;        // 65536 = 2^16
constexpr int kNVEC = kB * kHW4;     // 2097152 float4-groups of pixels
constexpr long long kNPIX = (long long)kB * kHW;  // 8388608

constexpr int kThreads = 256;
constexpr int kBlocks  = kNVEC / kThreads;   // 8192, exact: 1 group per thread

// ws layout: kReps replicas of 13 accumulator slots, each slot on its own
// 64B line. Slot (rep, i) at float index (rep*13 + i) * 16.
constexpr int kReps = 32;
constexpr int kSlotStride = 16;
constexpr int kWsFloats = kReps * 13 * kSlotStride;   // 6656 floats = 26 KiB

__global__ __launch_bounds__(kThreads) void loss_main(const float* __restrict__ logits,
                                                      const int* __restrict__ tgt,
                                                      float* __restrict__ ws) {
    const int tid = blockIdx.x * kThreads + threadIdx.x;   // == group index, exact
    const int b   = tid >> 16;              // tid / kHW4
    const int hw4 = tid & (kHW4 - 1);
    const int base = b * (kC * kHW4) + hw4; // float4-unit index

    const float4* lg4 = reinterpret_cast<const float4*>(logits);
    float4 a0 = lg4[base];
    float4 a1 = lg4[base + kHW4];
    float4 a2 = lg4[base + 2 * kHW4];
    float4 a3 = lg4[base + 3 * kHW4];
    int4 t4 = reinterpret_cast<const int4*>(tgt)[tid];

    float ce = 0.f;
    float ps0 = 0.f, ps1 = 0.f, ps2 = 0.f, ps3 = 0.f;
    float it0 = 0.f, it1 = 0.f, it2 = 0.f, it3 = 0.f;
    unsigned cnt = 0;   // 4 packed byte counters (≤4 per class per thread)

    auto px = [&](float x0, float x1, float x2, float x3, int t) {
        float m  = fmaxf(fmaxf(x0, x1), fmaxf(x2, x3));
        float e0 = __expf(x0 - m);
        float e1 = __expf(x1 - m);
        float e2 = __expf(x2 - m);
        float e3 = __expf(x3 - m);
        float se = e0 + e1 + e2 + e3;
        float inv = __builtin_amdgcn_rcpf(se);
        float xt = (t == 0) ? x0 : (t == 1) ? x1 : (t == 2) ? x2 : x3;
        ce += __logf(se) + (m - xt);
        float p0 = e0 * inv, p1 = e1 * inv, p2 = e2 * inv, p3 = e3 * inv;
        ps0 += p0; ps1 += p1; ps2 += p2; ps3 += p3;
        it0 += (t == 0) ? p0 : 0.f;
        it1 += (t == 1) ? p1 : 0.f;
        it2 += (t == 2) ? p2 : 0.f;
        it3 += (t == 3) ? p3 : 0.f;
        cnt += 1u << (t * 8);
    };
    px(a0.x, a1.x, a2.x, a3.x, t4.x);
    px(a0.y, a1.y, a2.y, a3.y, t4.y);
    px(a0.z, a1.z, a2.z, a3.z, t4.z);
    px(a0.w, a1.w, a2.w, a3.w, t4.w);

    float ct0 = (float)(cnt & 0xff);
    float ct1 = (float)((cnt >> 8) & 0xff);
    float ct2 = (float)((cnt >> 16) & 0xff);
    float ct3 = (float)((cnt >> 24) & 0xff);

    // ---- Block reduction: shuffle tree per wave, LDS across 4 waves ----
    float vals[13] = {ce, ps0, ps1, ps2, ps3, it0, it1, it2, it3, ct0, ct1, ct2, ct3};
    #pragma unroll
    for (int i = 0; i < 13; ++i) {
        float v = vals[i];
        #pragma unroll
        for (int off = 32; off > 0; off >>= 1) v += __shfl_down(v, off);
        vals[i] = v;
    }
    __shared__ float smem[4][13];
    int lane = threadIdx.x & 63;
    int wave = threadIdx.x >> 6;
    if (lane == 0) {
        #pragma unroll
        for (int i = 0; i < 13; ++i) smem[wave][i] = vals[i];
    }
    __syncthreads();
    if (threadIdx.x < 13) {
        float s = smem[0][threadIdx.x] + smem[1][threadIdx.x] +
                  smem[2][threadIdx.x] + smem[3][threadIdx.x];
        int rep = blockIdx.x & (kReps - 1);
        atomicAdd(&ws[(rep * 13 + threadIdx.x) * kSlotStride], s);
    }
}

__global__ void finalize_kernel(const float* __restrict__ ws, float* __restrict__ out) {
    __shared__ float tot[13];
    if (threadIdx.x < 13) {
        float s = 0.f;
        #pragma unroll
        for (int r = 0; r < kReps; ++r) s += ws[(r * 13 + threadIdx.x) * kSlotStride];
        tot[threadIdx.x] = s;
    }
    __syncthreads();
    if (threadIdx.x == 0) {
        float ce_m = tot[0] / (float)kNPIX;
        float dsum = 0.f;
        #pragma unroll
        for (int c = 0; c < 4; ++c) {
            float I = tot[5 + c];
            float U = tot[1 + c] + tot[9 + c];
            dsum += 1.f - (2.f * I + SMOOTH) / (U + SMOOTH);
        }
        float dice = dsum * 0.25f;
        out[0] = ALPHA * ce_m + BETA * dice;
        out[1] = 1.f - dice;
    }
}

extern "C" void kernel_launch(void* const* d_in, const int* in_sizes, int n_in,
                              void* d_out, int out_size, void* d_ws, size_t ws_size,
                              hipStream_t stream) {
    const float* logits = (const float*)d_in[0];
    const int*   tgt    = (const int*)d_in[1];
    float* out = (float*)d_out;
    float* ws  = (float*)d_ws;

    hipMemsetAsync(ws, 0, kWsFloats * sizeof(float), stream);
    loss_main<<<kBlocks, kThreads, 0, stream>>>(logits, tgt, ws);
    finalize_kernel<<<1, 64, 0, stream>>>(ws, out);
}